// Round 1
// baseline (808.017 us; speedup 1.0000x reference)
//
#include <hip/hip_runtime.h>

// ---------------------------------------------------------------------------
// PatchCore pipeline on MI355X (gfx950)
//   coreset [50000,1024] f32, features [3136,1024] f32
//   1) convert both to bf16 (padded M->50048, Q->3200), row norms in f32
//   2) fused GEMM(bf16 MFMA) + min over M of (a2[m] - 2*ab)  -> atomicMin keys
//   3) finalize: dist = sqrt(max(min + b2[q],0)); image max per batch
//   4) bilinear 28->224 (jax.image.resize semantics), gaussian blur sigma=4
//      radius=16 with numpy 'reflect' padding, separable W then H
// Workspace budget ~110.9 MB.
// ---------------------------------------------------------------------------

typedef unsigned short ushort_t;
typedef unsigned int uint32;
typedef __bf16 bf16x8 __attribute__((ext_vector_type(8)));
typedef float f32x4 __attribute__((ext_vector_type(4)));

#define M_ROWS 50000
#define M_PAD  50048   // 391 * 128
#define M_TILES 391
#define Q_ROWS 3136
#define Q_PAD  3200    // 25 * 128
#define Q_TILES 25
#define DDIM   1024
#define FLT_BIG 3.402823466e+38f

typedef __attribute__((address_space(1))) const void* as1_cvoid;
typedef __attribute__((address_space(3))) void* as3_void;

__device__ __forceinline__ void load16_lds(const void* g, void* l) {
  // width=16 global->LDS DMA; LDS dest is wave-uniform base + lane*16
  __builtin_amdgcn_global_load_lds((as1_cvoid)g, (as3_void)l, 16, 0, 0);
}

__device__ __forceinline__ ushort_t f2bf(float f) {  // RNE f32 -> bf16
  uint32 u = __float_as_uint(f);
  u += 0x7FFFu + ((u >> 16) & 1u);
  return (ushort_t)(u >> 16);
}
// order-preserving float <-> uint key (handles negatives)
__device__ __forceinline__ uint32 f2key(float f) {
  uint32 b = __float_as_uint(f);
  return (b & 0x80000000u) ? ~b : (b | 0x80000000u);
}
__device__ __forceinline__ float key2f(uint32 k) {
  uint32 b = (k & 0x80000000u) ? (k ^ 0x80000000u) : ~k;
  return __uint_as_float(b);
}

// --------------------------------------------------------------------- init
__global__ void k_init(uint32* __restrict__ mk) {
  int i = blockIdx.x * 256 + threadIdx.x;
  if (i < Q_PAD) mk[i] = 0xFFFFFFFFu;  // decodes to +FLT_MAX
}

// ----------------------------------------------------- f32 -> bf16 + norms
// one block per (padded) row; 256 threads * float4 = 1024 elems
__global__ void k_convert(const float* __restrict__ src, ushort_t* __restrict__ dst,
                          float* __restrict__ norm, int valid_rows, float pad_norm) {
  const int row = blockIdx.x;
  const int tid = threadIdx.x;
  if (row < valid_rows) {
    const float4 v = ((const float4*)(src + (size_t)row * DDIM))[tid];
    float ss = v.x * v.x + v.y * v.y + v.z * v.z + v.w * v.w;
    ushort4 o;
    o.x = f2bf(v.x); o.y = f2bf(v.y); o.z = f2bf(v.z); o.w = f2bf(v.w);
    ((ushort4*)(dst + (size_t)row * DDIM))[tid] = o;
    #pragma unroll
    for (int off = 32; off; off >>= 1) ss += __shfl_xor(ss, off);
    __shared__ float wsum[4];
    if ((tid & 63) == 0) wsum[tid >> 6] = ss;
    __syncthreads();
    if (tid == 0) norm[row] = wsum[0] + wsum[1] + wsum[2] + wsum[3];
  } else {
    ushort4 z; z.x = z.y = z.z = z.w = 0;
    ((ushort4*)(dst + (size_t)row * DDIM))[tid] = z;
    if (tid == 0) norm[row] = pad_norm;
  }
}

// ------------------------------------------- fused bf16 GEMM + min over M
// m97-style: 128x128 tile, BK=64, 4 waves (2x2), 4x4 16x16x32 frags/wave
__global__ __launch_bounds__(256) void k_gemm_min(
    const ushort_t* __restrict__ A,   // coreset bf16 [M_PAD][1024]
    const ushort_t* __restrict__ B,   // features bf16 [Q_PAD][1024]
    const float* __restrict__ a2, const float* __restrict__ b2,
    uint32* __restrict__ mk) {
  __shared__ __align__(16) ushort_t As[128 * 64];
  __shared__ __align__(16) ushort_t Bs[128 * 64];
  __shared__ float a2s[128];
  __shared__ float red[2][64];

  const int tid = threadIdx.x;
  const int lane = tid & 63;
  const int wid = tid >> 6;
  const int wr = wid >> 1;   // wave row (m half)
  const int wc = wid & 1;    // wave col (q half)
  const int m0 = blockIdx.y * 128;
  const int q0 = blockIdx.x * 128;

  if (tid < 128) a2s[tid] = a2[m0 + tid];

  f32x4 acc[4][4];
  #pragma unroll
  for (int i = 0; i < 4; ++i)
    #pragma unroll
    for (int j = 0; j < 4; ++j)
      #pragma unroll
      for (int e = 0; e < 4; ++e) acc[i][j][e] = 0.f;

  const int kb = lane >> 4;     // k-group 0..3
  const int col = lane & 15;    // fragment row/col
  const int srow = tid >> 3;    // staging: row within 32-row slab
  const int scb = tid & 7;      // staging: 16B chunk within row

  for (int kt = 0; kt < DDIM / 64; ++kt) {
    const int kbase = kt * 64;
    #pragma unroll
    for (int it = 0; it < 4; ++it) {
      const int row = it * 32 + srow;
      const ushort_t* ga = A + (size_t)(m0 + row) * DDIM + kbase + scb * 8;
      const ushort_t* gb = B + (size_t)(q0 + row) * DDIM + kbase + scb * 8;
      // wave-uniform LDS base; lanes land at base + lane*16 (linear layout)
      ushort_t* la = As + (size_t)(it * 256 + wid * 64) * 8;
      ushort_t* lb = Bs + (size_t)(it * 256 + wid * 64) * 8;
      load16_lds(ga, la);
      load16_lds(gb, lb);
    }
    __syncthreads();
    #pragma unroll
    for (int kk = 0; kk < 2; ++kk) {
      bf16x8 af[4], bfr[4];
      #pragma unroll
      for (int i = 0; i < 4; ++i)
        af[i] = *reinterpret_cast<const bf16x8*>(
            &As[(wr * 64 + i * 16 + col) * 64 + kk * 32 + kb * 8]);
      #pragma unroll
      for (int j = 0; j < 4; ++j)
        bfr[j] = *reinterpret_cast<const bf16x8*>(
            &Bs[(wc * 64 + j * 16 + col) * 64 + kk * 32 + kb * 8]);
      #pragma unroll
      for (int i = 0; i < 4; ++i)
        #pragma unroll
        for (int j = 0; j < 4; ++j)
          acc[i][j] = __builtin_amdgcn_mfma_f32_16x16x32_bf16(af[i], bfr[j],
                                                              acc[i][j], 0, 0, 0);
    }
    __syncthreads();
  }

  // epilogue: per-lane min over 16 m's per q, then lane-group and wave-row
  // reduce. C/D layout: col = lane&15 (q), row = (lane>>4)*4 + reg (m).
  float v[4];
  #pragma unroll
  for (int j = 0; j < 4; ++j) {
    float mn = FLT_BIG;
    #pragma unroll
    for (int i = 0; i < 4; ++i)
      #pragma unroll
      for (int r = 0; r < 4; ++r) {
        const int ml = wr * 64 + i * 16 + kb * 4 + r;
        mn = fminf(mn, a2s[ml] - 2.0f * acc[i][j][r]);
      }
    mn = fminf(mn, __shfl_xor(mn, 16));
    mn = fminf(mn, __shfl_xor(mn, 32));
    v[j] = mn;
  }
  if (wr == 1 && lane < 16) {
    #pragma unroll
    for (int j = 0; j < 4; ++j) red[wc][j * 16 + lane] = v[j];
  }
  __syncthreads();
  if (wr == 0 && lane < 16) {
    #pragma unroll
    for (int j = 0; j < 4; ++j) {
      const int q = q0 + wc * 64 + j * 16 + lane;
      const float s = fminf(v[j], red[wc][j * 16 + lane]) + b2[q];
      atomicMin(&mk[q], f2key(s));
    }
  }
}

// ------------------------------------- patch scores (sqrt) + image maxes
__global__ void k_finalize(const uint32* __restrict__ mk, float* __restrict__ ps,
                           float* __restrict__ out_scores) {
  const int b = blockIdx.x;     // 4 blocks
  const int tid = threadIdx.x;  // 256
  float vmax = -FLT_BIG;
  for (int t = tid; t < 784; t += 256) {
    const int q = b * 784 + t;
    float s = fmaxf(key2f(mk[q]), 0.f);
    const float p = sqrtf(s);
    ps[q] = p;
    vmax = fmaxf(vmax, p);
  }
  #pragma unroll
  for (int off = 32; off; off >>= 1) vmax = fmaxf(vmax, __shfl_xor(vmax, off));
  __shared__ float wm[4];
  if ((tid & 63) == 0) wm[tid >> 6] = vmax;
  __syncthreads();
  if (tid == 0) out_scores[b] = fmaxf(fmaxf(wm[0], wm[1]), fmaxf(wm[2], wm[3]));
}

// ------------------------- bilinear 28->224, jax.image.resize semantics
__global__ void k_upsample(const float* __restrict__ ps, float* __restrict__ up) {
  const int idx = blockIdx.x * 256 + threadIdx.x;
  if (idx >= 4 * 224 * 224) return;
  const int x = idx % 224;
  const int y = (idx / 224) % 224;
  const int b = idx / (224 * 224);
  float fx = (x + 0.5f) * 0.125f - 0.5f;
  float fy = (y + 0.5f) * 0.125f - 0.5f;
  int ix = (int)floorf(fx); float wx = fx - (float)ix;
  int iy = (int)floorf(fy); float wy = fy - (float)iy;
  if (ix < 0)  { ix = 0;  wx = 0.f; }
  if (ix >= 27){ ix = 27; wx = 0.f; }
  if (iy < 0)  { iy = 0;  wy = 0.f; }
  if (iy >= 27){ iy = 27; wy = 0.f; }
  const int ix1 = min(ix + 1, 27), iy1 = min(iy + 1, 27);
  const float* g = ps + b * 784;
  const float v00 = g[iy * 28 + ix],  v01 = g[iy * 28 + ix1];
  const float v10 = g[iy1 * 28 + ix], v11 = g[iy1 * 28 + ix1];
  const float v0 = (1.f - wx) * v00 + wx * v01;
  const float v1 = (1.f - wx) * v10 + wx * v11;
  up[idx] = (1.f - wy) * v0 + wy * v1;
}

// --------------------- gaussian blur sigma=4 r=16, numpy 'reflect' padding
__device__ __forceinline__ int reflect224(int i) {
  if (i < 0) i = -i;
  if (i > 223) i = 446 - i;
  return i;
}

__global__ void k_blur_w(const float* __restrict__ in, float* __restrict__ out) {
  const int idx = blockIdx.x * 256 + threadIdx.x;
  if (idx >= 4 * 224 * 224) return;
  const int x = idx % 224;
  const int rowbase = idx - x;
  float w[33], wsum = 0.f;
  #pragma unroll
  for (int t = 0; t < 33; ++t) {
    const float d = (float)(t - 16);
    w[t] = __expf(0.f) * expf(-0.03125f * d * d);  // exp(-0.5*(d/4)^2)
    wsum += w[t];
  }
  float s = 0.f;
  #pragma unroll
  for (int t = 0; t < 33; ++t) s += w[t] * in[rowbase + reflect224(x + t - 16)];
  out[idx] = s / wsum;
}

__global__ void k_blur_h(const float* __restrict__ in, float* __restrict__ out) {
  const int idx = blockIdx.x * 256 + threadIdx.x;
  if (idx >= 4 * 224 * 224) return;
  const int x = idx % 224;
  const int y = (idx / 224) % 224;
  const int b = idx / (224 * 224);
  float w[33], wsum = 0.f;
  #pragma unroll
  for (int t = 0; t < 33; ++t) {
    const float d = (float)(t - 16);
    w[t] = expf(-0.03125f * d * d);
    wsum += w[t];
  }
  const float* plane = in + b * 224 * 224;
  float s = 0.f;
  #pragma unroll
  for (int t = 0; t < 33; ++t) s += w[t] * plane[reflect224(y + t - 16) * 224 + x];
  out[idx] = s / wsum;
}

// ---------------------------------------------------------------- launch
extern "C" void kernel_launch(void* const* d_in, const int* in_sizes, int n_in,
                              void* d_out, int out_size, void* d_ws, size_t ws_size,
                              hipStream_t stream) {
  const float* cs = (const float*)d_in[0];
  const float* ft = (const float*)d_in[1];
  float* out = (float*)d_out;  // [4] image scores, then [4*224*224] masks

  // workspace layout (bytes)
  const size_t OFF_FT = (size_t)M_PAD * DDIM * 2;            // 102,498,304
  const size_t OFF_A2 = OFF_FT + (size_t)Q_PAD * DDIM * 2;   // 109,051,904
  const size_t OFF_B2 = OFF_A2 + (size_t)M_PAD * 4;          // 109,252,096
  const size_t OFF_MK = OFF_B2 + (size_t)Q_PAD * 4;          // 109,264,896
  const size_t OFF_PS = OFF_MK + (size_t)Q_PAD * 4;          // 109,277,696
  const size_t OFF_UP = OFF_PS + (size_t)Q_ROWS * 4;         // 109,290,240
  const size_t OFF_TM = OFF_UP + (size_t)4 * 224 * 224 * 4;  // 110,093,056
  // total = OFF_TM + 802,816 = 110,895,872 bytes

  char* ws = (char*)d_ws;
  ushort_t* csb = (ushort_t*)(ws);
  ushort_t* ftb = (ushort_t*)(ws + OFF_FT);
  float* a2 = (float*)(ws + OFF_A2);
  float* b2 = (float*)(ws + OFF_B2);
  uint32* mk = (uint32*)(ws + OFF_MK);
  float* ps = (float*)(ws + OFF_PS);
  float* up = (float*)(ws + OFF_UP);
  float* tm = (float*)(ws + OFF_TM);

  k_init<<<(Q_PAD + 255) / 256, 256, 0, stream>>>(mk);
  k_convert<<<M_PAD, 256, 0, stream>>>(cs, csb, a2, M_ROWS, FLT_BIG);
  k_convert<<<Q_PAD, 256, 0, stream>>>(ft, ftb, b2, Q_ROWS, 0.f);
  k_gemm_min<<<dim3(Q_TILES, M_TILES), 256, 0, stream>>>(csb, ftb, a2, b2, mk);
  k_finalize<<<4, 256, 0, stream>>>(mk, ps, out);
  k_upsample<<<784, 256, 0, stream>>>(ps, up);
  k_blur_w<<<784, 256, 0, stream>>>(up, tm);
  k_blur_h<<<784, 256, 0, stream>>>(tm, out + 4);
}

// Round 2
// 761.769 us; speedup vs baseline: 1.0607x; 1.0607x over previous
//
#include <hip/hip_runtime.h>

// ---------------------------------------------------------------------------
// PatchCore pipeline on MI355X (gfx950) — round 2
//   GEMM: 128x128 tile, BK=64, min-2-phase dbuf (stage t+1 before compute t,
//         ONE barrier/K-step), T2 both-sides XOR swizzle (linear LDS dest,
//         pre-swizzled global source, swizzled ds_read), bijective XCD chunk.
//   Tail: combined blur∘bilinear axis matrix C[224][28], two 28-MAC passes.
// ---------------------------------------------------------------------------

typedef unsigned short ushort_t;
typedef unsigned int uint32;
typedef __bf16 bf16x8 __attribute__((ext_vector_type(8)));
typedef float f32x4 __attribute__((ext_vector_type(4)));

#define M_ROWS 50000
#define M_PAD  50048   // 391 * 128
#define M_TILES 391
#define Q_ROWS 3136
#define Q_PAD  3200    // 25 * 128
#define Q_TILES 25
#define DDIM   1024
#define NKT    (DDIM / 64)
#define FLT_BIG 3.402823466e+38f

typedef __attribute__((address_space(1))) const void* as1_cvoid;
typedef __attribute__((address_space(3))) void* as3_void;

__device__ __forceinline__ void load16_lds(const void* g, void* l) {
  // width=16 global->LDS DMA; LDS dest is wave-uniform base + lane*16 (linear)
  __builtin_amdgcn_global_load_lds((as1_cvoid)g, (as3_void)l, 16, 0, 0);
}

__device__ __forceinline__ ushort_t f2bf(float f) {  // RNE f32 -> bf16
  uint32 u = __float_as_uint(f);
  u += 0x7FFFu + ((u >> 16) & 1u);
  return (ushort_t)(u >> 16);
}
// order-preserving float <-> uint key
__device__ __forceinline__ uint32 f2key(float f) {
  uint32 b = __float_as_uint(f);
  return (b & 0x80000000u) ? ~b : (b | 0x80000000u);
}
__device__ __forceinline__ float key2f(uint32 k) {
  uint32 b = (k & 0x80000000u) ? (k ^ 0x80000000u) : ~k;
  return __uint_as_float(b);
}

// --------------------------------------------------------------------- init
__global__ void k_init(uint32* __restrict__ mk) {
  int i = blockIdx.x * 256 + threadIdx.x;
  if (i < Q_PAD) mk[i] = 0xFFFFFFFFu;  // decodes to +FLT_MAX
}

// ---------------------------------------------- f32 -> bf16 + norms (wave/row)
__global__ void k_convert(const float* __restrict__ src, ushort_t* __restrict__ dst,
                          float* __restrict__ norm, int valid_rows, float pad_norm) {
  const int row = blockIdx.x * 4 + (threadIdx.x >> 6);
  const int lane = threadIdx.x & 63;
  if (row < valid_rows) {
    const float4* s = (const float4*)(src + (size_t)row * DDIM);
    ushort4* d = (ushort4*)(dst + (size_t)row * DDIM);
    float ss = 0.f;
    #pragma unroll
    for (int u = 0; u < 4; ++u) {
      const float4 v = s[lane + 64 * u];
      ss += v.x * v.x + v.y * v.y + v.z * v.z + v.w * v.w;
      ushort4 o;
      o.x = f2bf(v.x); o.y = f2bf(v.y); o.z = f2bf(v.z); o.w = f2bf(v.w);
      d[lane + 64 * u] = o;
    }
    #pragma unroll
    for (int off = 32; off; off >>= 1) ss += __shfl_xor(ss, off);
    if (lane == 0) norm[row] = ss;
  } else {
    ushort4 z; z.x = z.y = z.z = z.w = 0;
    ushort4* d = (ushort4*)(dst + (size_t)row * DDIM);
    #pragma unroll
    for (int u = 0; u < 4; ++u) d[lane + 64 * u] = z;
    if (lane == 0) norm[row] = pad_norm;
  }
}

// ------------------------------------------- fused bf16 GEMM + min over M
// 128x128 tile, BK=64, 4 waves (2x2), 4x4 16x16x32 frags/wave, dbuf LDS.
__global__ __launch_bounds__(256) void k_gemm_min(
    const ushort_t* __restrict__ A,   // coreset bf16 [M_PAD][1024]
    const ushort_t* __restrict__ B,   // features bf16 [Q_PAD][1024]
    const float* __restrict__ a2, const float* __restrict__ b2,
    uint32* __restrict__ mk) {
  __shared__ __align__(16) ushort_t As[2][128 * 64];
  __shared__ __align__(16) ushort_t Bs[2][128 * 64];
  __shared__ float a2s[128];
  __shared__ float red[2][64];

  const int tid = threadIdx.x;
  const int lane = tid & 63;
  const int wid = tid >> 6;
  const int wr = wid >> 1;
  const int wc = wid & 1;

  // bijective XCD chunking: each XCD owns a contiguous band of M-tiles,
  // Q-tiles fastest -> A-tile read once per XCD band (L2-resident reuse).
  const int nwg = M_TILES * Q_TILES;      // 9775
  const int q8 = nwg >> 3, r8 = nwg & 7;  // 1221, 7
  const int w = blockIdx.x;
  const int xcd = w & 7, idx = w >> 3;
  const int nw = (xcd < r8 ? xcd * (q8 + 1) : r8 * (q8 + 1) + (xcd - r8) * q8) + idx;
  const int mt = nw / Q_TILES;
  const int qt = nw - mt * Q_TILES;
  const int m0 = mt * 128;
  const int q0 = qt * 128;

  if (tid < 128) a2s[tid] = a2[m0 + tid];

  f32x4 acc[4][4];
  #pragma unroll
  for (int i = 0; i < 4; ++i)
    #pragma unroll
    for (int j = 0; j < 4; ++j)
      #pragma unroll
      for (int e = 0; e < 4; ++e) acc[i][j][e] = 0.f;

  const int kb = lane >> 4;     // k-group 0..3
  const int col = lane & 15;    // fragment row/col
  const int swz = col & 7;      // read-side swizzle = (lds_row & 7)
  const int srow = tid >> 3;    // staging row within 32-row slab (0..31)
  const int scb = tid & 7;      // staging 16B chunk (0..7)
  const int ssw = scb ^ (srow & 7);  // pre-swizzled source chunk

  // stage one K-tile (BK=64) into buffer p: linear LDS dest, swizzled source
  #define STAGE(p, kbase_)                                                   \
    {                                                                        \
      _Pragma("unroll")                                                      \
      for (int it = 0; it < 4; ++it) {                                       \
        const int row_ = it * 32 + srow;                                     \
        load16_lds(A + (size_t)(m0 + row_) * DDIM + (kbase_) + ssw * 8,      \
                   &As[p][it * 2048 + wid * 512]);                           \
        load16_lds(B + (size_t)(q0 + row_) * DDIM + (kbase_) + ssw * 8,      \
                   &Bs[p][it * 2048 + wid * 512]);                           \
      }                                                                      \
    }

  STAGE(0, 0)
  __syncthreads();  // drains vmcnt(0): tile 0 resident

  for (int kt = 0; kt < NKT; ++kt) {
    const int cur = kt & 1;
    if (kt + 1 < NKT) STAGE(cur ^ 1, (kt + 1) * 64)   // overlap with compute
    #pragma unroll
    for (int kk = 0; kk < 2; ++kk) {
      bf16x8 af[4], bfr[4];
      #pragma unroll
      for (int i = 0; i < 4; ++i)
        af[i] = *reinterpret_cast<const bf16x8*>(
            &As[cur][(wr * 64 + i * 16 + col) * 64 + ((kk * 4 + kb) ^ swz) * 8]);
      #pragma unroll
      for (int j = 0; j < 4; ++j)
        bfr[j] = *reinterpret_cast<const bf16x8*>(
            &Bs[cur][(wc * 64 + j * 16 + col) * 64 + ((kk * 4 + kb) ^ swz) * 8]);
      #pragma unroll
      for (int i = 0; i < 4; ++i)
        #pragma unroll
        for (int j = 0; j < 4; ++j)
          acc[i][j] = __builtin_amdgcn_mfma_f32_16x16x32_bf16(af[i], bfr[j],
                                                              acc[i][j], 0, 0, 0);
    }
    __syncthreads();  // implicit vmcnt(0)+lgkmcnt(0): next tile resident
  }

  // epilogue: min over m for each q. C/D: col=lane&15 (q), row=(lane>>4)*4+r (m)
  float v[4];
  #pragma unroll
  for (int j = 0; j < 4; ++j) {
    float mn = FLT_BIG;
    #pragma unroll
    for (int i = 0; i < 4; ++i)
      #pragma unroll
      for (int r = 0; r < 4; ++r) {
        const int ml = wr * 64 + i * 16 + kb * 4 + r;
        mn = fminf(mn, a2s[ml] - 2.0f * acc[i][j][r]);
      }
    mn = fminf(mn, __shfl_xor(mn, 16));
    mn = fminf(mn, __shfl_xor(mn, 32));
    v[j] = mn;
  }
  if (wr == 1 && lane < 16) {
    #pragma unroll
    for (int j = 0; j < 4; ++j) red[wc][j * 16 + lane] = v[j];
  }
  __syncthreads();
  if (wr == 0 && lane < 16) {
    #pragma unroll
    for (int j = 0; j < 4; ++j) {
      const int q = q0 + wc * 64 + j * 16 + lane;
      const float s = fminf(v[j], red[wc][j * 16 + lane]) + b2[q];
      atomicMin(&mk[q], f2key(s));
    }
  }
}

// ------------------------------------- patch scores (sqrt) + image maxes
__global__ void k_finalize(const uint32* __restrict__ mk, float* __restrict__ ps,
                           float* __restrict__ out_scores) {
  const int b = blockIdx.x;     // 4
  const int tid = threadIdx.x;  // 256
  float vmax = -FLT_BIG;
  for (int t = tid; t < 784; t += 256) {
    const int q = b * 784 + t;
    float s = fmaxf(key2f(mk[q]), 0.f);
    const float p = sqrtf(s);
    ps[q] = p;
    vmax = fmaxf(vmax, p);
  }
  #pragma unroll
  for (int off = 32; off; off >>= 1) vmax = fmaxf(vmax, __shfl_xor(vmax, off));
  __shared__ float wm[4];
  if ((tid & 63) == 0) wm[tid >> 6] = vmax;
  __syncthreads();
  if (tid == 0) out_scores[b] = fmaxf(fmaxf(wm[0], wm[1]), fmaxf(wm[2], wm[3]));
}

// ---------------- combined axis matrix: C[o][g] = sum_t blur[t]*bilin(o+t-16,g)
__device__ __forceinline__ int reflect224(int i) {
  if (i < 0) i = -i;
  if (i > 223) i = 446 - i;
  return i;
}

__global__ void k_mkC(float* __restrict__ C) {
  const int idx = blockIdx.x * 256 + threadIdx.x;
  if (idx >= 224 * 28) return;
  const int o = idx / 28;
  const int g = idx - o * 28;
  float acc = 0.f, wsum = 0.f;
  for (int t = 0; t < 33; ++t) {
    const float d = (float)(t - 16);
    const float wb = expf(-0.03125f * d * d);
    wsum += wb;
    const int y = reflect224(o + t - 16);
    float fy = ((float)y + 0.5f) * 0.125f - 0.5f;
    int iy = (int)floorf(fy);
    float wy = fy - (float)iy;
    if (iy < 0)   { iy = 0;  wy = 0.f; }
    if (iy >= 27) { iy = 27; wy = 0.f; }
    const int iy1 = min(iy + 1, 27);
    float bw = 0.f;
    if (g == iy)  bw += 1.f - wy;
    if (g == iy1) bw += wy;
    acc += wb * bw;
  }
  C[idx] = acc / wsum;
}

// T[b][gy][X] = sum_gx C[X][gx] * ps[b][gy][gx]
__global__ void k_mask1(const float* __restrict__ ps, const float* __restrict__ C,
                        float* __restrict__ T) {
  const int idx = blockIdx.x * 256 + threadIdx.x;
  if (idx >= 4 * 28 * 224) return;
  const int X = idx % 224;
  const int gy = (idx / 224) % 28;
  const int b = idx / (224 * 28);
  const float* Crow = C + X * 28;
  const float* prow = ps + (b * 28 + gy) * 28;
  float s = 0.f;
  #pragma unroll
  for (int gx = 0; gx < 28; ++gx) s += Crow[gx] * prow[gx];
  T[idx] = s;
}

// masks[b][Y][X] = sum_gy C[Y][gy] * T[b][gy][X]
__global__ void k_mask2(const float* __restrict__ T, const float* __restrict__ C,
                        float* __restrict__ out) {
  const int idx = blockIdx.x * 256 + threadIdx.x;
  if (idx >= 4 * 224 * 224) return;
  const int X = idx % 224;
  const int Y = (idx / 224) % 224;
  const int b = idx / (224 * 224);
  const float* Crow = C + Y * 28;
  float s = 0.f;
  #pragma unroll
  for (int gy = 0; gy < 28; ++gy) s += Crow[gy] * T[(b * 28 + gy) * 224 + X];
  out[idx] = s;
}

// ---------------------------------------------------------------- launch
extern "C" void kernel_launch(void* const* d_in, const int* in_sizes, int n_in,
                              void* d_out, int out_size, void* d_ws, size_t ws_size,
                              hipStream_t stream) {
  const float* cs = (const float*)d_in[0];
  const float* ft = (const float*)d_in[1];
  float* out = (float*)d_out;  // [4] image scores, then [4*224*224] masks

  const size_t OFF_FT = (size_t)M_PAD * DDIM * 2;            // 102,498,304
  const size_t OFF_A2 = OFF_FT + (size_t)Q_PAD * DDIM * 2;   // 109,051,904
  const size_t OFF_B2 = OFF_A2 + (size_t)M_PAD * 4;          // 109,252,096
  const size_t OFF_MK = OFF_B2 + (size_t)Q_PAD * 4;          // 109,264,896
  const size_t OFF_PS = OFF_MK + (size_t)Q_PAD * 4;          // 109,277,696
  const size_t OFF_C  = OFF_PS + (size_t)Q_ROWS * 4;         // 109,290,240
  const size_t OFF_T  = OFF_C + (size_t)224 * 28 * 4;        // 109,315,328
  // end = OFF_T + 4*28*224*4 = 109,415,680 bytes (< prior 110.9 MB layout)

  char* ws = (char*)d_ws;
  ushort_t* csb = (ushort_t*)(ws);
  ushort_t* ftb = (ushort_t*)(ws + OFF_FT);
  float* a2 = (float*)(ws + OFF_A2);
  float* b2 = (float*)(ws + OFF_B2);
  uint32* mk = (uint32*)(ws + OFF_MK);
  float* ps = (float*)(ws + OFF_PS);
  float* C  = (float*)(ws + OFF_C);
  float* T  = (float*)(ws + OFF_T);

  k_init<<<(Q_PAD + 255) / 256, 256, 0, stream>>>(mk);
  k_convert<<<M_PAD / 4, 256, 0, stream>>>(cs, csb, a2, M_ROWS, FLT_BIG);
  k_convert<<<Q_PAD / 4, 256, 0, stream>>>(ft, ftb, b2, Q_ROWS, 0.f);
  k_gemm_min<<<M_TILES * Q_TILES, 256, 0, stream>>>(csb, ftb, a2, b2, mk);
  k_finalize<<<4, 256, 0, stream>>>(mk, ps, out);
  k_mkC<<<(224 * 28 + 255) / 256, 256, 0, stream>>>(C);
  k_mask1<<<(4 * 28 * 224 + 255) / 256, 256, 0, stream>>>(ps, C, T);
  k_mask2<<<(4 * 224 * 224 + 255) / 256, 256, 0, stream>>>(T, C, out + 4);
}

// Round 5
// 649.687 us; speedup vs baseline: 1.2437x; 1.1725x over previous
//
#include <hip/hip_runtime.h>

// ---------------------------------------------------------------------------
// PatchCore pipeline on MI355X (gfx950) — round 5 (round 3/4 schedule with the
// macro-scoping compile fix: KTILE binds a local `buf` so nested LDA/LDB
// macros resolve it; CPP substitutes parameters only in the macro's own body,
// not in nested expansions during rescan).
//   GEMM: 256x256 tile, BK=64, 8 waves (2Mx4N), 8-phase-per-2-K-tiles schedule
//         (T3+T4: counted vmcnt(6), raw s_barrier, never drain-to-0 mid-loop;
//          T5 setprio around MFMA; T2 both-sides XOR swizzle; T1 XCD chunk).
//   Liveness ledger (per K-tile t, phases ph0..ph3, buf = t&1):
//     reads : ph0 = B-all + A rows {0-31,128-159}; ph1 = A {32-63,160-191};
//             ph2 = A {64-95,192-223}; ph3 = A {96-127,224-255}
//     deaths: buf.B after ph0; buf.A-lo {0-63,128-191} after ph1;
//             buf.A-hi {64-127,192-255} after ph3
//     stage : ph0 -> (t+1).A-hi (other buf, dead since t-1.ph3)
//             ph1 -> (t+2).B-lo ; ph2 -> (t+2).B-hi ; ph3 -> (t+2).A-lo
//     wait  : end of ph3: vmcnt(6) drains exactly through (t+1).A-hi,
//             leaves (t+2).{B,A-lo} = 6 loads in flight.
// ---------------------------------------------------------------------------

typedef unsigned short ushort_t;
typedef unsigned int uint32;
typedef __bf16 bf16x8 __attribute__((ext_vector_type(8)));
typedef float f32x4 __attribute__((ext_vector_type(4)));

#define M_ROWS 50000
#define M_PAD  50176   // 196 * 256
#define M_TILES 196
#define Q_ROWS 3136
#define Q_PAD  3328    // 13 * 256
#define Q_TILES 13
#define DDIM   1024
#define NKT    16      // 1024 / 64
#define FLT_BIG 3.402823466e+38f

typedef __attribute__((address_space(1))) const void* as1_cvoid;
typedef __attribute__((address_space(3))) void* as3_void;

__device__ __forceinline__ void load16_lds(const void* g, void* l) {
  __builtin_amdgcn_global_load_lds((as1_cvoid)g, (as3_void)l, 16, 0, 0);
}

__device__ __forceinline__ ushort_t f2bf(float f) {  // RNE f32 -> bf16
  uint32 u = __float_as_uint(f);
  u += 0x7FFFu + ((u >> 16) & 1u);
  return (ushort_t)(u >> 16);
}
__device__ __forceinline__ uint32 f2key(float f) {
  uint32 b = __float_as_uint(f);
  return (b & 0x80000000u) ? ~b : (b | 0x80000000u);
}
__device__ __forceinline__ float key2f(uint32 k) {
  uint32 b = (k & 0x80000000u) ? (k ^ 0x80000000u) : ~k;
  return __uint_as_float(b);
}

#define WAITVM6 asm volatile("s_waitcnt vmcnt(6)" ::: "memory")
#define WAITVM0 asm volatile("s_waitcnt vmcnt(0)" ::: "memory")
#define WAITVM8 asm volatile("s_waitcnt vmcnt(8)" ::: "memory")
#define LGKM0   asm volatile("s_waitcnt lgkmcnt(0)" ::: "memory")
#define BAR()   __builtin_amdgcn_s_barrier()

// --------------------------------------------------------------------- init
__global__ void k_init(uint32* __restrict__ mk) {
  int i = blockIdx.x * 256 + threadIdx.x;
  if (i < Q_PAD) mk[i] = 0xFFFFFFFFu;  // +FLT_MAX key
}

// ---------------------------------------------- f32 -> bf16 + norms (wave/row)
__global__ void k_convert(const float* __restrict__ src, ushort_t* __restrict__ dst,
                          float* __restrict__ norm, int valid_rows, float pad_norm) {
  const int row = blockIdx.x * 4 + (threadIdx.x >> 6);
  const int lane = threadIdx.x & 63;
  if (row < valid_rows) {
    const float4* s = (const float4*)(src + (size_t)row * DDIM);
    ushort4* d = (ushort4*)(dst + (size_t)row * DDIM);
    float ss = 0.f;
    #pragma unroll
    for (int u = 0; u < 4; ++u) {
      const float4 v = s[lane + 64 * u];
      ss += v.x * v.x + v.y * v.y + v.z * v.z + v.w * v.w;
      ushort4 o;
      o.x = f2bf(v.x); o.y = f2bf(v.y); o.z = f2bf(v.z); o.w = f2bf(v.w);
      d[lane + 64 * u] = o;
    }
    #pragma unroll
    for (int off = 32; off; off >>= 1) ss += __shfl_xor(ss, off);
    if (lane == 0) norm[row] = ss;
  } else {
    ushort4 z; z.x = z.y = z.z = z.w = 0;
    ushort4* d = (ushort4*)(dst + (size_t)row * DDIM);
    #pragma unroll
    for (int u = 0; u < 4; ++u) d[lane + 64 * u] = z;
    if (lane == 0) norm[row] = pad_norm;
  }
}

// ------------------------------------------- fused bf16 GEMM + min over M
__global__ __launch_bounds__(512, 2) void k_gemm_min(
    const ushort_t* __restrict__ A,   // coreset bf16 [M_PAD][1024]
    const ushort_t* __restrict__ B,   // features bf16 [Q_PAD][1024]
    const float* __restrict__ a2, const float* __restrict__ b2,
    uint32* __restrict__ mk) {
  __shared__ __align__(16) ushort_t As[2][256 * 64];  // 64 KB
  __shared__ __align__(16) ushort_t Bs[2][256 * 64];  // 64 KB
  __shared__ float a2s[256];
  __shared__ float red[4][64];

  const int tid = threadIdx.x;
  const int lane = tid & 63;
  const int wid = tid >> 6;     // 0..7
  const int wr = wid >> 2;      // 0..1 (m half: rows wr*128..+127)
  const int wc = wid & 3;       // 0..3 (q slice: cols wc*64..+63)

  // T1: bijective XCD chunking (M-band per XCD, Q fastest)
  const int nwg = M_TILES * Q_TILES;      // 2548
  const int q8 = nwg >> 3, r8 = nwg & 7;  // 318, 4
  const int w = blockIdx.x;
  const int xcd = w & 7, idx = w >> 3;
  const int nw = (xcd < r8 ? xcd * (q8 + 1) : r8 * (q8 + 1) + (xcd - r8) * q8) + idx;
  const int mt = nw / Q_TILES;
  const int qt = nw - mt * Q_TILES;
  const int m0 = mt * 256;
  const int q0 = qt * 256;

  if (tid < 256) a2s[tid] = a2[m0 + tid];

  f32x4 acc[8][4];
  #pragma unroll
  for (int i = 0; i < 8; ++i)
    #pragma unroll
    for (int j = 0; j < 4; ++j)
      #pragma unroll
      for (int e = 0; e < 4; ++e) acc[i][j][e] = 0.f;

  const int kb = lane >> 4;     // 0..3
  const int col = lane & 15;
  const int swz = col & 7;      // read-side swizzle (= lds_row & 7)

  // staging: thread t -> row (t>>3), pre-swizzled chunk (t&7)^((t>>3)&7)
  const int swc = (tid & 7) ^ ((tid >> 3) & 7);
  const ushort_t* Abase = A + (size_t)(m0 + (tid >> 3)) * DDIM + swc * 8;
  const ushort_t* Bbase = B + (size_t)(q0 + (tid >> 3)) * DDIM + swc * 8;
  const int ldsoff = wid * 512;  // elems: wave-uniform 1KB slot within granule

  // stage a 64-row (8KB) granule of K-tile v into buffer bufi at rows row0..
  #define STG_A(bufi, row0, v) \
    load16_lds(Abase + (size_t)(row0) * DDIM + (v) * 64, &As[bufi][(row0) * 64] + ldsoff)
  #define STG_B(bufi, row0, v) \
    load16_lds(Bbase + (size_t)(row0) * DDIM + (v) * 64, &Bs[bufi][(row0) * 64] + ldsoff)

  // frag loads (swizzled read, conflict-free; `buf` is KTILE's block-local)
  #define LDA(row, kk) (*reinterpret_cast<const bf16x8*>( \
      &As[buf][(row) * 64 + ((((kk) * 4 + kb) ^ swz) << 3)]))
  #define LDB(row, kk) (*reinterpret_cast<const bf16x8*>( \
      &Bs[buf][(row) * 64 + ((((kk) * 4 + kb) ^ swz) << 3)]))

  // ---- prologue: fully stage tiles 0 (buf0) and 1 (buf1)
  STG_B(0, 0, 0);   STG_B(0, 64, 0);  STG_B(0, 128, 0); STG_B(0, 192, 0);
  STG_A(0, 0, 0);   STG_A(0, 128, 0); STG_A(0, 64, 0);  STG_A(0, 192, 0);
  STG_B(1, 0, 1);   STG_B(1, 64, 1);  STG_B(1, 128, 1); STG_B(1, 192, 1);
  STG_A(1, 0, 1);   STG_A(1, 128, 1); STG_A(1, 64, 1);  STG_A(1, 192, 1);
  WAITVM8;  // drain tile 0 (8 loads); tile 1's 8 stay in flight
  BAR();

  #define MFMA_ROW(q_)                                                        \
    _Pragma("unroll")                                                         \
    for (int m = 0; m < 2; ++m)                                               \
      _Pragma("unroll")                                                       \
      for (int n = 0; n < 4; ++n)                                             \
        _Pragma("unroll")                                                     \
        for (int kk = 0; kk < 2; ++kk)                                        \
          acc[(q_) * 2 + m][n] = __builtin_amdgcn_mfma_f32_16x16x32_bf16(     \
              af[m][kk], bff[n][kk], acc[(q_) * 2 + m][n], 0, 0, 0);

  #define KTILE(t, bufp_)                                                     \
  {                                                                           \
    const int buf = (bufp_);                                                  \
    bf16x8 bff[4][2], af[2][2];                                               \
    /* ---- ph0: B-all + A m01; stage (t+1).A-hi */                           \
    _Pragma("unroll")                                                         \
    for (int n = 0; n < 4; ++n)                                               \
      _Pragma("unroll")                                                       \
      for (int kk = 0; kk < 2; ++kk) bff[n][kk] = LDB(wc * 64 + n * 16 + col, kk); \
    _Pragma("unroll")                                                         \
    for (int m = 0; m < 2; ++m)                                               \
      _Pragma("unroll")                                                       \
      for (int kk = 0; kk < 2; ++kk) af[m][kk] = LDA(wr * 128 + m * 16 + col, kk); \
    if ((t) >= 1 && (t) <= NKT - 2) {                                         \
      STG_A(buf ^ 1, 64, (t) + 1); STG_A(buf ^ 1, 192, (t) + 1);              \
    }                                                                         \
    BAR(); LGKM0;                                                             \
    __builtin_amdgcn_s_setprio(1); MFMA_ROW(0); __builtin_amdgcn_s_setprio(0);\
    BAR();                                                                    \
    /* ---- ph1: A m23; stage (t+2).B-lo */                                   \
    _Pragma("unroll")                                                         \
    for (int m = 0; m < 2; ++m)                                               \
      _Pragma("unroll")                                                       \
      for (int kk = 0; kk < 2; ++kk)                                          \
        af[m][kk] = LDA(wr * 128 + 32 + m * 16 + col, kk);                    \
    if ((t) <= NKT - 3) { STG_B(buf, 0, (t) + 2); STG_B(buf, 64, (t) + 2); }  \
    BAR(); LGKM0;                                                             \
    __builtin_amdgcn_s_setprio(1); MFMA_ROW(1); __builtin_amdgcn_s_setprio(0);\
    BAR();                                                                    \
    /* ---- ph2: A m45; stage (t+2).B-hi */                                   \
    _Pragma("unroll")                                                         \
    for (int m = 0; m < 2; ++m)                                               \
      _Pragma("unroll")                                                       \
      for (int kk = 0; kk < 2; ++kk)                                          \
        af[m][kk] = LDA(wr * 128 + 64 + m * 16 + col, kk);                    \
    if ((t) <= NKT - 3) { STG_B(buf, 128, (t) + 2); STG_B(buf, 192, (t) + 2);}\
    BAR(); LGKM0;                                                             \
    __builtin_amdgcn_s_setprio(1); MFMA_ROW(2); __builtin_amdgcn_s_setprio(0);\
    BAR();                                                                    \
    /* ---- ph3: A m67; stage (t+2).A-lo; counted wait before close */        \
    _Pragma("unroll")                                                         \
    for (int m = 0; m < 2; ++m)                                               \
      _Pragma("unroll")                                                       \
      for (int kk = 0; kk < 2; ++kk)                                          \
        af[m][kk] = LDA(wr * 128 + 96 + m * 16 + col, kk);                    \
    if ((t) <= NKT - 3) { STG_A(buf, 0, (t) + 2); STG_A(buf, 128, (t) + 2); } \
    BAR(); LGKM0;                                                             \
    __builtin_amdgcn_s_setprio(1); MFMA_ROW(3); __builtin_amdgcn_s_setprio(0);\
    if ((t) <= NKT - 3) { WAITVM6; }                                          \
    else if ((t) == NKT - 2) { WAITVM0; }                                     \
    BAR();                                                                    \
  }

  for (int tt = 0; tt < NKT / 2; ++tt) {
    const int te = 2 * tt;
    KTILE(te, 0)
    KTILE(te + 1, 1)
  }

  // ---- epilogue: min over m per q column
  float v[4];
  #pragma unroll
  for (int j = 0; j < 4; ++j) {
    float mn = FLT_BIG;
    #pragma unroll
    for (int i = 0; i < 8; ++i)
      #pragma unroll
      for (int r = 0; r < 4; ++r) {
        const int ml = wr * 128 + i * 16 + kb * 4 + r;
        mn = fminf(mn, a2s[ml] - 2.0f * acc[i][j][r]);
      }
    mn = fminf(mn, __shfl_xor(mn, 16));
    mn = fminf(mn, __shfl_xor(mn, 32));
    v[j] = mn;
  }
  if (wr == 1 && lane < 16) {
    #pragma unroll
    for (int j = 0; j < 4; ++j) red[wc][j * 16 + lane] = v[j];
  }
  __syncthreads();
  if (wr == 0 && lane < 16) {
    #pragma unroll
    for (int j = 0; j < 4; ++j) {
      const int q = q0 + wc * 64 + j * 16 + lane;
      const float s = fminf(v[j], red[wc][j * 16 + lane]) + b2[q];
      atomicMin(&mk[q], f2key(s));
    }
  }
}

// ------------------------------------- patch scores (sqrt) + image maxes
__global__ void k_finalize(const uint32* __restrict__ mk, float* __restrict__ ps,
                           float* __restrict__ out_scores) {
  const int b = blockIdx.x;
  const int tid = threadIdx.x;
  float vmax = -FLT_BIG;
  for (int t = tid; t < 784; t += 256) {
    const int q = b * 784 + t;
    float s = fmaxf(key2f(mk[q]), 0.f);
    const float p = sqrtf(s);
    ps[q] = p;
    vmax = fmaxf(vmax, p);
  }
  #pragma unroll
  for (int off = 32; off; off >>= 1) vmax = fmaxf(vmax, __shfl_xor(vmax, off));
  __shared__ float wm[4];
  if ((tid & 63) == 0) wm[tid >> 6] = vmax;
  __syncthreads();
  if (tid == 0) out_scores[b] = fmaxf(fmaxf(wm[0], wm[1]), fmaxf(wm[2], wm[3]));
}

// ---------------- combined axis matrix: C[o][g] = sum_t blur[t]*bilin(o+t-16,g)
__device__ __forceinline__ int reflect224(int i) {
  if (i < 0) i = -i;
  if (i > 223) i = 446 - i;
  return i;
}

__global__ void k_mkC(float* __restrict__ C) {
  const int idx = blockIdx.x * 256 + threadIdx.x;
  if (idx >= 224 * 28) return;
  const int o = idx / 28;
  const int g = idx - o * 28;
  float acc = 0.f, wsum = 0.f;
  for (int t = 0; t < 33; ++t) {
    const float d = (float)(t - 16);
    const float wb = expf(-0.03125f * d * d);
    wsum += wb;
    const int y = reflect224(o + t - 16);
    float fy = ((float)y + 0.5f) * 0.125f - 0.5f;
    int iy = (int)floorf(fy);
    float wy = fy - (float)iy;
    if (iy < 0)   { iy = 0;  wy = 0.f; }
    if (iy >= 27) { iy = 27; wy = 0.f; }
    const int iy1 = min(iy + 1, 27);
    float bw = 0.f;
    if (g == iy)  bw += 1.f - wy;
    if (g == iy1) bw += wy;
    acc += wb * bw;
  }
  C[idx] = acc / wsum;
}

__global__ void k_mask1(const float* __restrict__ ps, const float* __restrict__ C,
                        float* __restrict__ T) {
  const int idx = blockIdx.x * 256 + threadIdx.x;
  if (idx >= 4 * 28 * 224) return;
  const int X = idx % 224;
  const int gy = (idx / 224) % 28;
  const int b = idx / (224 * 28);
  const float* Crow = C + X * 28;
  const float* prow = ps + (b * 28 + gy) * 28;
  float s = 0.f;
  #pragma unroll
  for (int gx = 0; gx < 28; ++gx) s += Crow[gx] * prow[gx];
  T[idx] = s;
}

__global__ void k_mask2(const float* __restrict__ T, const float* __restrict__ C,
                        float* __restrict__ out) {
  const int idx = blockIdx.x * 256 + threadIdx.x;
  if (idx >= 4 * 224 * 224) return;
  const int X = idx % 224;
  const int Y = (idx / 224) % 224;
  const int b = idx / (224 * 224);
  const float* Crow = C + Y * 28;
  float s = 0.f;
  #pragma unroll
  for (int gy = 0; gy < 28; ++gy) s += Crow[gy] * T[(b * 28 + gy) * 224 + X];
  out[idx] = s;
}

// ---------------------------------------------------------------- launch
extern "C" void kernel_launch(void* const* d_in, const int* in_sizes, int n_in,
                              void* d_out, int out_size, void* d_ws, size_t ws_size,
                              hipStream_t stream) {
  const float* cs = (const float*)d_in[0];
  const float* ft = (const float*)d_in[1];
  float* out = (float*)d_out;  // [4] scores, then [4*224*224] masks

  const size_t OFF_FT = (size_t)M_PAD * DDIM * 2;            // 102,760,448
  const size_t OFF_A2 = OFF_FT + (size_t)Q_PAD * DDIM * 2;   // 109,576,192
  const size_t OFF_B2 = OFF_A2 + (size_t)M_PAD * 4;          // 109,776,896
  const size_t OFF_MK = OFF_B2 + (size_t)Q_PAD * 4;          // 109,790,208
  const size_t OFF_PS = OFF_MK + (size_t)Q_PAD * 4;          // 109,803,520
  const size_t OFF_C  = OFF_PS + (size_t)Q_ROWS * 4;         // 109,816,064
  const size_t OFF_T  = OFF_C + (size_t)224 * 28 * 4;        // 109,841,152
  // end = OFF_T + 4*28*224*4 = 109,941,504 bytes

  char* ws = (char*)d_ws;
  ushort_t* csb = (ushort_t*)(ws);
  ushort_t* ftb = (ushort_t*)(ws + OFF_FT);
  float* a2 = (float*)(ws + OFF_A2);
  float* b2 = (float*)(ws + OFF_B2);
  uint32* mk = (uint32*)(ws + OFF_MK);
  float* ps = (float*)(ws + OFF_PS);
  float* C  = (float*)(ws + OFF_C);
  float* T  = (float*)(ws + OFF_T);

  k_init<<<(Q_PAD + 255) / 256, 256, 0, stream>>>(mk);
  k_convert<<<M_PAD / 4, 256, 0, stream>>>(cs, csb, a2, M_ROWS, FLT_BIG);
  k_convert<<<Q_PAD / 4, 256, 0, stream>>>(ft, ftb, b2, Q_ROWS, 0.f);
  k_gemm_min<<<M_TILES * Q_TILES, 512, 0, stream>>>(csb, ftb, a2, b2, mk);
  k_finalize<<<4, 256, 0, stream>>>(mk, ps, out);
  k_mkC<<<(224 * 28 + 255) / 256, 256, 0, stream>>>(C);
  k_mask1<<<(4 * 28 * 224 + 255) / 256, 256, 0, stream>>>(ps, C, T);
  k_mask2<<<(4 * 224 * 224 + 255) / 256, 256, 0, stream>>>(T, C, out + 4);
}

// Round 6
// 636.272 us; speedup vs baseline: 1.2699x; 1.0211x over previous
//
#include <hip/hip_runtime.h>

// ---------------------------------------------------------------------------
// PatchCore pipeline on MI355X (gfx950) — round 6
//   GEMM: 256x256 tile, BK=64, 8 waves (2Mx4N). Round-5 schedule + frag-read
//   software pipelining: every MFMA cluster consumes fragments ds_read one
//   barrier-region earlier, so LDS latency hides under MFMA (the round-5
//   profile showed 41% MfmaUtil with 0 conflicts / 12% HBM / 17% VALU —
//   residual was exposed ds_read latency between barrier-locked phases).
//   Per-tile region layout (buf = t&1):
//     R0: read afB=af1      ; MFMA0(afA=af0)       | BAR
//     S0: stage (t+1).A-hi                          | BAR
//     R1: read afA=af2      ; MFMA1(afB)            | BAR
//     S1: stage (t+2).B-lo                          | BAR
//     R2: read afB=af3      ; MFMA2(afA)            | BAR
//     S2: stage (t+2).B-hi                          | BAR
//     S3: stage (t+2).A-lo  ; vmcnt(6)              | BAR   <- drains ALL t+1
//     R3: MFMA3(afB)        ; prefetch bff,af0(t+1) | BAR
//   vmcnt FIFO ledger at S3(t): carried 6 [t+1.B-lo,B-hi,A-lo] + S0(t)
//   [t+1.A-hi] + S1..S3(t) [t+2.B,A-lo] = 14 -> vmcnt(6) completes the 8
//   oldest = all of tile t+1; BAR makes every wave's portion visible before
//   any wave's R3 prefetch reads it.  t=NKT-2: vmcnt(0); t=NKT-1: no wait.
// ---------------------------------------------------------------------------

typedef unsigned short ushort_t;
typedef unsigned int uint32;
typedef __bf16 bf16x8 __attribute__((ext_vector_type(8)));
typedef float f32x4 __attribute__((ext_vector_type(4)));

#define M_ROWS 50000
#define M_PAD  50176   // 196 * 256
#define M_TILES 196
#define Q_ROWS 3136
#define Q_PAD  3328    // 13 * 256
#define Q_TILES 13
#define DDIM   1024
#define NKT    16      // 1024 / 64
#define FLT_BIG 3.402823466e+38f

typedef __attribute__((address_space(1))) const void* as1_cvoid;
typedef __attribute__((address_space(3))) void* as3_void;

__device__ __forceinline__ void load16_lds(const void* g, void* l) {
  __builtin_amdgcn_global_load_lds((as1_cvoid)g, (as3_void)l, 16, 0, 0);
}

__device__ __forceinline__ ushort_t f2bf(float f) {  // RNE f32 -> bf16
  uint32 u = __float_as_uint(f);
  u += 0x7FFFu + ((u >> 16) & 1u);
  return (ushort_t)(u >> 16);
}
__device__ __forceinline__ uint32 f2key(float f) {
  uint32 b = __float_as_uint(f);
  return (b & 0x80000000u) ? ~b : (b | 0x80000000u);
}
__device__ __forceinline__ float key2f(uint32 k) {
  uint32 b = (k & 0x80000000u) ? (k ^ 0x80000000u) : ~k;
  return __uint_as_float(b);
}

#define WAITVM6 asm volatile("s_waitcnt vmcnt(6)" ::: "memory")
#define WAITVM0 asm volatile("s_waitcnt vmcnt(0)" ::: "memory")
#define WAITVM8 asm volatile("s_waitcnt vmcnt(8)" ::: "memory")
#define BAR()   __builtin_amdgcn_s_barrier()

// --------------------------------------------------------------------- init
__global__ void k_init(uint32* __restrict__ mk) {
  int i = blockIdx.x * 256 + threadIdx.x;
  if (i < Q_PAD) mk[i] = 0xFFFFFFFFu;  // +FLT_MAX key
}

// ---------------------------------------------- f32 -> bf16 + norms (wave/row)
__global__ void k_convert(const float* __restrict__ src, ushort_t* __restrict__ dst,
                          float* __restrict__ norm, int valid_rows, float pad_norm) {
  const int row = blockIdx.x * 4 + (threadIdx.x >> 6);
  const int lane = threadIdx.x & 63;
  if (row < valid_rows) {
    const float4* s = (const float4*)(src + (size_t)row * DDIM);
    ushort4* d = (ushort4*)(dst + (size_t)row * DDIM);
    float ss = 0.f;
    #pragma unroll
    for (int u = 0; u < 4; ++u) {
      const float4 v = s[lane + 64 * u];
      ss += v.x * v.x + v.y * v.y + v.z * v.z + v.w * v.w;
      ushort4 o;
      o.x = f2bf(v.x); o.y = f2bf(v.y); o.z = f2bf(v.z); o.w = f2bf(v.w);
      d[lane + 64 * u] = o;
    }
    #pragma unroll
    for (int off = 32; off; off >>= 1) ss += __shfl_xor(ss, off);
    if (lane == 0) norm[row] = ss;
  } else {
    ushort4 z; z.x = z.y = z.z = z.w = 0;
    ushort4* d = (ushort4*)(dst + (size_t)row * DDIM);
    #pragma unroll
    for (int u = 0; u < 4; ++u) d[lane + 64 * u] = z;
    if (lane == 0) norm[row] = pad_norm;
  }
}

// ------------------------------------------- fused bf16 GEMM + min over M
__global__ __launch_bounds__(512, 2) void k_gemm_min(
    const ushort_t* __restrict__ A,   // coreset bf16 [M_PAD][1024]
    const ushort_t* __restrict__ B,   // features bf16 [Q_PAD][1024]
    const float* __restrict__ a2, const float* __restrict__ b2,
    uint32* __restrict__ mk) {
  __shared__ __align__(16) ushort_t As[2][256 * 64];  // 64 KB
  __shared__ __align__(16) ushort_t Bs[2][256 * 64];  // 64 KB
  __shared__ float a2s[256];
  __shared__ float red[4][64];

  const int tid = threadIdx.x;
  const int lane = tid & 63;
  const int wid = tid >> 6;     // 0..7
  const int wr = wid >> 2;      // 0..1 (m half: rows wr*128..+127)
  const int wc = wid & 3;       // 0..3 (q slice: cols wc*64..+63)

  // T1: bijective XCD chunking (M-band per XCD, Q fastest)
  const int nwg = M_TILES * Q_TILES;      // 2548
  const int q8 = nwg >> 3, r8 = nwg & 7;  // 318, 4
  const int w = blockIdx.x;
  const int xcd = w & 7, idx = w >> 3;
  const int nw = (xcd < r8 ? xcd * (q8 + 1) : r8 * (q8 + 1) + (xcd - r8) * q8) + idx;
  const int mt = nw / Q_TILES;
  const int qt = nw - mt * Q_TILES;
  const int m0 = mt * 256;
  const int q0 = qt * 256;

  if (tid < 256) a2s[tid] = a2[m0 + tid];

  f32x4 acc[8][4];
  #pragma unroll
  for (int i = 0; i < 8; ++i)
    #pragma unroll
    for (int j = 0; j < 4; ++j)
      #pragma unroll
      for (int e = 0; e < 4; ++e) acc[i][j][e] = 0.f;

  const int kb = lane >> 4;     // 0..3
  const int col = lane & 15;
  const int swz = col & 7;      // read-side swizzle (= lds_row & 7)

  // staging: thread t -> row (t>>3), pre-swizzled chunk (t&7)^((t>>3)&7)
  const int swc = (tid & 7) ^ ((tid >> 3) & 7);
  const ushort_t* Abase = A + (size_t)(m0 + (tid >> 3)) * DDIM + swc * 8;
  const ushort_t* Bbase = B + (size_t)(q0 + (tid >> 3)) * DDIM + swc * 8;
  const int ldsoff = wid * 512;  // elems: wave-uniform 1KB slot within granule

  #define STG_A(bufi, row0, v) \
    load16_lds(Abase + (size_t)(row0) * DDIM + (v) * 64, &As[bufi][(row0) * 64] + ldsoff)
  #define STG_B(bufi, row0, v) \
    load16_lds(Bbase + (size_t)(row0) * DDIM + (v) * 64, &Bs[bufi][(row0) * 64] + ldsoff)

  // frag loads (swizzled read, conflict-free), explicit buffer index
  #define LDAf(bi, row, kk) (*reinterpret_cast<const bf16x8*>( \
      &As[bi][(row) * 64 + ((((kk) * 4 + kb) ^ swz) << 3)]))
  #define LDBf(bi, row, kk) (*reinterpret_cast<const bf16x8*>( \
      &Bs[bi][(row) * 64 + ((((kk) * 4 + kb) ^ swz) << 3)]))

  bf16x8 bff[4][2];             // B-frags of current tile (read 1 tile ahead)
  bf16x8 afA[2][2], afB[2][2];  // rotating A-frag buffers

  #define READ_BFF(bi)                                                        \
    _Pragma("unroll")                                                         \
    for (int n = 0; n < 4; ++n)                                               \
      _Pragma("unroll")                                                       \
      for (int kk = 0; kk < 2; ++kk)                                          \
        bff[n][kk] = LDBf(bi, wc * 64 + n * 16 + col, kk);

  #define READ_AF(dst_, bi, mbase_)                                           \
    _Pragma("unroll")                                                         \
    for (int m = 0; m < 2; ++m)                                               \
      _Pragma("unroll")                                                       \
      for (int kk = 0; kk < 2; ++kk)                                          \
        dst_[m][kk] = LDAf(bi, wr * 128 + (mbase_) + m * 16 + col, kk);

  #define MFMA_Q(q_, af_)                                                     \
    _Pragma("unroll")                                                         \
    for (int m = 0; m < 2; ++m)                                               \
      _Pragma("unroll")                                                       \
      for (int n = 0; n < 4; ++n)                                             \
        _Pragma("unroll")                                                     \
        for (int kk = 0; kk < 2; ++kk)                                        \
          acc[(q_) * 2 + m][n] = __builtin_amdgcn_mfma_f32_16x16x32_bf16(     \
              af_[m][kk], bff[n][kk], acc[(q_) * 2 + m][n], 0, 0, 0);

  // ---- prologue: stage tiles 0 (first 8 ops) and 1; prefetch tile-0 frags
  STG_B(0, 0, 0);   STG_B(0, 64, 0);  STG_B(0, 128, 0); STG_B(0, 192, 0);
  STG_A(0, 0, 0);   STG_A(0, 64, 0);  STG_A(0, 128, 0); STG_A(0, 192, 0);
  STG_B(1, 0, 1);   STG_B(1, 64, 1);  STG_B(1, 128, 1); STG_B(1, 192, 1);
  STG_A(1, 0, 1);   STG_A(1, 64, 1);  STG_A(1, 128, 1); STG_A(1, 192, 1);
  WAITVM8;  // tile 0 resident; tile 1's 8 in flight
  BAR();
  READ_BFF(0);
  READ_AF(afA, 0, 0);   // af0 of tile 0

  #define KTILE(t, bufp_)                                                     \
  {                                                                           \
    const int buf = (bufp_);                                                  \
    /* R0 */                                                                  \
    __builtin_amdgcn_s_setprio(1);                                            \
    READ_AF(afB, buf, 32);                                                    \
    MFMA_Q(0, afA);                                                           \
    __builtin_amdgcn_s_setprio(0);                                            \
    BAR();                                                                    \
    /* S0 */                                                                  \
    if ((t) >= 1 && (t) <= NKT - 2) {                                         \
      STG_A(buf ^ 1, 64, (t) + 1); STG_A(buf ^ 1, 192, (t) + 1);              \
    }                                                                         \
    BAR();                                                                    \
    /* R1 */                                                                  \
    __builtin_amdgcn_s_setprio(1);                                            \
    READ_AF(afA, buf, 64);                                                    \
    MFMA_Q(1, afB);                                                           \
    __builtin_amdgcn_s_setprio(0);                                            \
    BAR();                                                                    \
    /* S1 */                                                                  \
    if ((t) <= NKT - 3) { STG_B(buf, 0, (t) + 2); STG_B(buf, 64, (t) + 2); }  \
    BAR();                                                                    \
    /* R2 */                                                                  \
    __builtin_amdgcn_s_setprio(1);                                            \
    READ_AF(afB, buf, 96);                                                    \
    MFMA_Q(2, afA);                                                           \
    __builtin_amdgcn_s_setprio(0);                                            \
    BAR();                                                                    \
    /* S2 */                                                                  \
    if ((t) <= NKT - 3) { STG_B(buf, 128, (t) + 2); STG_B(buf, 192, (t) + 2);}\
    BAR();                                                                    \
    /* S3 + counted wait (drains ALL of tile t+1) */                          \
    if ((t) <= NKT - 3) {                                                     \
      STG_A(buf, 0, (t) + 2); STG_A(buf, 128, (t) + 2);                       \
      WAITVM6;                                                                \
    } else if ((t) == NKT - 2) {                                              \
      WAITVM0;                                                                \
    }                                                                         \
    BAR();                                                                    \
    /* R3: last MFMA of tile t, then prefetch tile t+1's ph0 frags */         \
    __builtin_amdgcn_s_setprio(1);                                            \
    MFMA_Q(3, afB);                                                           \
    if ((t) <= NKT - 2) { READ_BFF(buf ^ 1); READ_AF(afA, buf ^ 1, 0); }      \
    __builtin_amdgcn_s_setprio(0);                                            \
    BAR();                                                                    \
  }

  for (int tt = 0; tt < NKT / 2; ++tt) {
    const int te = 2 * tt;
    KTILE(te, 0)
    KTILE(te + 1, 1)
  }

  // ---- epilogue: min over m per q column
  float v[4];
  #pragma unroll
  for (int j = 0; j < 4; ++j) {
    float mn = FLT_BIG;
    #pragma unroll
    for (int i = 0; i < 8; ++i)
      #pragma unroll
      for (int r = 0; r < 4; ++r) {
        const int ml = wr * 128 + i * 16 + kb * 4 + r;
        mn = fminf(mn, a2s[ml] - 2.0f * acc[i][j][r]);
      }
    mn = fminf(mn, __shfl_xor(mn, 16));
    mn = fminf(mn, __shfl_xor(mn, 32));
    v[j] = mn;
  }
  if (wr == 1 && lane < 16) {
    #pragma unroll
    for (int j = 0; j < 4; ++j) red[wc][j * 16 + lane] = v[j];
  }
  __syncthreads();
  if (wr == 0 && lane < 16) {
    #pragma unroll
    for (int j = 0; j < 4; ++j) {
      const int q = q0 + wc * 64 + j * 16 + lane;
      const float s = fminf(v[j], red[wc][j * 16 + lane]) + b2[q];
      atomicMin(&mk[q], f2key(s));
    }
  }
}

// ------------------------------------- patch scores (sqrt) + image maxes
__global__ void k_finalize(const uint32* __restrict__ mk, float* __restrict__ ps,
                           float* __restrict__ out_scores) {
  const int b = blockIdx.x;
  const int tid = threadIdx.x;
  float vmax = -FLT_BIG;
  for (int t = tid; t < 784; t += 256) {
    const int q = b * 784 + t;
    float s = fmaxf(key2f(mk[q]), 0.f);
    const float p = sqrtf(s);
    ps[q] = p;
    vmax = fmaxf(vmax, p);
  }
  #pragma unroll
  for (int off = 32; off; off >>= 1) vmax = fmaxf(vmax, __shfl_xor(vmax, off));
  __shared__ float wm[4];
  if ((tid & 63) == 0) wm[tid >> 6] = vmax;
  __syncthreads();
  if (tid == 0) out_scores[b] = fmaxf(fmaxf(wm[0], wm[1]), fmaxf(wm[2], wm[3]));
}

// ---------------- combined axis matrix: C[o][g] = sum_t blur[t]*bilin(o+t-16,g)
__device__ __forceinline__ int reflect224(int i) {
  if (i < 0) i = -i;
  if (i > 223) i = 446 - i;
  return i;
}

__global__ void k_mkC(float* __restrict__ C) {
  const int idx = blockIdx.x * 256 + threadIdx.x;
  if (idx >= 224 * 28) return;
  const int o = idx / 28;
  const int g = idx - o * 28;
  float acc = 0.f, wsum = 0.f;
  for (int t = 0; t < 33; ++t) {
    const float d = (float)(t - 16);
    const float wb = expf(-0.03125f * d * d);
    wsum += wb;
    const int y = reflect224(o + t - 16);
    float fy = ((float)y + 0.5f) * 0.125f - 0.5f;
    int iy = (int)floorf(fy);
    float wy = fy - (float)iy;
    if (iy < 0)   { iy = 0;  wy = 0.f; }
    if (iy >= 27) { iy = 27; wy = 0.f; }
    const int iy1 = min(iy + 1, 27);
    float bw = 0.f;
    if (g == iy)  bw += 1.f - wy;
    if (g == iy1) bw += wy;
    acc += wb * bw;
  }
  C[idx] = acc / wsum;
}

__global__ void k_mask1(const float* __restrict__ ps, const float* __restrict__ C,
                        float* __restrict__ T) {
  const int idx = blockIdx.x * 256 + threadIdx.x;
  if (idx >= 4 * 28 * 224) return;
  const int X = idx % 224;
  const int gy = (idx / 224) % 28;
  const int b = idx / (224 * 28);
  const float* Crow = C + X * 28;
  const float* prow = ps + (b * 28 + gy) * 28;
  float s = 0.f;
  #pragma unroll
  for (int gx = 0; gx < 28; ++gx) s += Crow[gx] * prow[gx];
  T[idx] = s;
}

__global__ void k_mask2(const float* __restrict__ T, const float* __restrict__ C,
                        float* __restrict__ out) {
  const int idx = blockIdx.x * 256 + threadIdx.x;
  if (idx >= 4 * 224 * 224) return;
  const int X = idx % 224;
  const int Y = (idx / 224) % 224;
  const int b = idx / (224 * 224);
  const float* Crow = C + Y * 28;
  float s = 0.f;
  #pragma unroll
  for (int gy = 0; gy < 28; ++gy) s += Crow[gy] * T[(b * 28 + gy) * 224 + X];
  out[idx] = s;
}

// ---------------------------------------------------------------- launch
extern "C" void kernel_launch(void* const* d_in, const int* in_sizes, int n_in,
                              void* d_out, int out_size, void* d_ws, size_t ws_size,
                              hipStream_t stream) {
  const float* cs = (const float*)d_in[0];
  const float* ft = (const float*)d_in[1];
  float* out = (float*)d_out;  // [4] scores, then [4*224*224] masks

  const size_t OFF_FT = (size_t)M_PAD * DDIM * 2;            // 102,760,448
  const size_t OFF_A2 = OFF_FT + (size_t)Q_PAD * DDIM * 2;   // 109,576,192
  const size_t OFF_B2 = OFF_A2 + (size_t)M_PAD * 4;          // 109,776,896
  const size_t OFF_MK = OFF_B2 + (size_t)Q_PAD * 4;          // 109,790,208
  const size_t OFF_PS = OFF_MK + (size_t)Q_PAD * 4;          // 109,803,520
  const size_t OFF_C  = OFF_PS + (size_t)Q_ROWS * 4;         // 109,816,064
  const size_t OFF_T  = OFF_C + (size_t)224 * 28 * 4;        // 109,841,152
  // end = OFF_T + 4*28*224*4 = 109,941,504 bytes

  char* ws = (char*)d_ws;
  ushort_t* csb = (ushort_t*)(ws);
  ushort_t* ftb = (ushort_t*)(ws + OFF_FT);
  float* a2 = (float*)(ws + OFF_A2);
  float* b2 = (float*)(ws + OFF_B2);
  uint32* mk = (uint32*)(ws + OFF_MK);
  float* ps = (float*)(ws + OFF_PS);
  float* C  = (float*)(ws + OFF_C);
  float* T  = (float*)(ws + OFF_T);

  k_init<<<(Q_PAD + 255) / 256, 256, 0, stream>>>(mk);
  k_convert<<<M_PAD / 4, 256, 0, stream>>>(cs, csb, a2, M_ROWS, FLT_BIG);
  k_convert<<<Q_PAD / 4, 256, 0, stream>>>(ft, ftb, b2, Q_ROWS, 0.f);
  k_gemm_min<<<M_TILES * Q_TILES, 512, 0, stream>>>(csb, ftb, a2, b2, mk);
  k_finalize<<<4, 256, 0, stream>>>(mk, ps, out);
  k_mkC<<<(224 * 28 + 255) / 256, 256, 0, stream>>>(C);
  k_mask1<<<(4 * 28 * 224 + 255) / 256, 256, 0, stream>>>(ps, C, T);
  k_mask2<<<(4 * 224 * 224 + 255) / 256, 256, 0, stream>>>(T, C, out + 4);
}